// Round 11
// baseline (262.632 us; speedup 1.0000x reference)
//
#include <hip/hip_runtime.h>

// MEASUREMENT ROUND: r7-validated pipeline, but row phase repeated 4x
// (3 dummy reps -> scratch buffers, real rep last). Purpose: expose the row
// kernel in rocprof top-5 (it always hid below the harness's ~152us fills)
// and pin T_row = (dur - 144.6)/3. Logic otherwise identical to round 7
// (passed, absmax 0.0).

typedef float f4 __attribute__((ext_vector_type(4)));

#define TILE_ROWS 256
#define ROW_F4    9   // 8 data f4 + 1 pad f4 -> conflict-free LDS b128 r/w
#define ROW_REPS  4

struct Ctrl {
    unsigned hist8[256];
    unsigned hist12[4096];
    unsigned bcnt[4096];     // low-12 counts within selected 20-bit prefix
    float    bsum[4096];     // nll sums per low-12 bucket
    unsigned pos_num;
    unsigned cnt;
    unsigned done;
    unsigned pad;
    double   sum;
};

__global__ void init_kernel(unsigned* w, int words) {
    for (int i = threadIdx.x + blockIdx.x * blockDim.x; i < words;
         i += blockDim.x * gridDim.x)
        w[i] = 0u;
}

// Wave-aggregated LDS histogram add (top byte has few distinct values).
__device__ inline void wave_hist_add(unsigned* h, unsigned bucket) {
    unsigned long long todo = __ballot(1);
    while (todo) {
        int leader = (int)__builtin_ctzll(todo);
        unsigned b = __shfl(bucket, leader);
        unsigned long long same = __ballot(bucket == b) & todo;
        if ((int)(threadIdx.x & 63) == leader)
            atomicAdd(&h[b], (unsigned)__popcll(same));
        todo &= ~same;
    }
}

__global__ void __launch_bounds__(256)
row_kernel(const f4* __restrict__ pred4, const int* __restrict__ label,
           unsigned* __restrict__ keys, float* __restrict__ nll,
           Ctrl* __restrict__ c, unsigned* __restrict__ keys_d,
           float* __restrict__ nll_d, Ctrl* __restrict__ cd, int n) {
    __shared__ f4 tile[TILE_ROWS * ROW_F4];   // 36 KB
    __shared__ unsigned h[256];
    __shared__ int wsum[4];
    const int tid = threadIdx.x;
    const int tile_stride = gridDim.x * TILE_ROWS;

    for (int rep = 0; rep < ROW_REPS; ++rep) {
        const bool real = (rep == ROW_REPS - 1);
        unsigned* K  = real ? keys : keys_d;
        float*    NL = real ? nll  : nll_d;
        Ctrl*     C  = real ? c    : cd;

        h[tid] = 0u;
        __syncthreads();
        int pos_local = 0;

        for (int tbase = blockIdx.x * TILE_ROWS; tbase < n; tbase += tile_stride) {
            // stage 256 rows x 128B, fully coalesced (4KB per instruction)
#pragma unroll
            for (int k = 0; k < 8; ++k) {
                int idx = (k << 8) + tid;                 // 0..2047
                f4 v = pred4[(size_t)tbase * 8 + idx];
                tile[(idx >> 3) * ROW_F4 + (idx & 7)] = v;
            }
            __syncthreads();

            int row = tbase + tid;
            float r[32];
#pragma unroll
            for (int j = 0; j < 8; ++j) {
                f4 v = tile[tid * ROW_F4 + j];
                r[4 * j + 0] = v.x; r[4 * j + 1] = v.y;
                r[4 * j + 2] = v.z; r[4 * j + 3] = v.w;
            }
            float m_nb = r[1];
#pragma unroll
            for (int j = 2; j < 32; ++j) m_nb = fmaxf(m_nb, r[j]);
            float m_all = fmaxf(m_nb, r[0]);

            float s = 0.f;
#pragma unroll
            for (int j = 0; j < 32; ++j) s += __expf(r[j] - m_all);

            int lab = label[row];
            int sl = lab; sl = sl < 0 ? 0 : sl; sl = sl > 31 ? 31 : sl;
            float xl = r[0];
#pragma unroll
            for (int j = 1; j < 32; ++j) xl = (j == sl) ? r[j] : xl;

            NL[row] = (m_all + __logf(s)) - xl;

            bool is_pos = (lab != 0);
            pos_local += is_pos ? 1 : 0;

            float ns = is_pos ? -__builtin_inff() : m_nb;
            unsigned u    = __float_as_uint(ns);
            unsigned ukey = (u & 0x80000000u) ? ~u : (u | 0x80000000u);
            unsigned dkey = ~ukey;             // ascending dkey = descending float
            K[row] = dkey;
            wave_hist_add(h, dkey >> 24);

            __syncthreads();   // protect tile before next stage
        }

#pragma unroll
        for (int off = 32; off > 0; off >>= 1)
            pos_local += __shfl_down(pos_local, off);
        int wid = tid >> 6;
        if ((tid & 63) == 0) wsum[wid] = pos_local;
        __syncthreads();
        if (tid == 0)
            atomicAdd(&C->pos_num,
                      (unsigned)(wsum[0] + wsum[1] + wsum[2] + wsum[3]));
        if (h[tid]) atomicAdd(&C->hist8[tid], h[tid]);
        __syncthreads();
    }
}

// 256-wide inclusive scan of s[] in LDS (blockDim.x == 256).
__device__ inline void block_scan256(unsigned* s) {
    const int t = threadIdx.x;
#pragma unroll
    for (int off = 1; off < 256; off <<= 1) {
        unsigned v = (t >= off) ? s[t - off] : 0u;
        __syncthreads();
        s[t] += v;
        __syncthreads();
    }
}

__device__ inline void rank_params(const Ctrl* c, int factor, int n,
                                   unsigned& rank, bool& use_thr) {
    long long pos     = (long long)c->pos_num;
    long long neg_sum = pos * (long long)factor;
    long long num_neg = (long long)n - pos;
    long long idx     = neg_sum - 1;
    if (idx < 0) idx = 0;
    if (idx > (long long)n - 1) idx = (long long)n - 1;
    rank    = (unsigned)idx;
    use_thr = (num_neg > neg_sum);
}

__device__ inline void select_byte3(const Ctrl* c, unsigned rank, unsigned* s,
                                    unsigned* shbr, unsigned& b3, unsigned& rank1) {
    const int t = threadIdx.x;
    unsigned cnt8 = c->hist8[t];
    s[t] = cnt8;
    __syncthreads();
    block_scan256(s);
    unsigned incl = s[t], excl = incl - cnt8;
    if (cnt8 > 0u && excl <= rank && rank < incl) {
        shbr[0] = (unsigned)t;
        shbr[1] = rank - excl;
    }
    __syncthreads();
    b3 = shbr[0];
    rank1 = shbr[1];
    __syncthreads();
}

__device__ inline void select_12(const unsigned* hist, unsigned rank_in,
                                 unsigned* s, unsigned* shbr,
                                 unsigned& sub, unsigned& rank_out) {
    const int t = threadIdx.x;
    unsigned lc[16]; unsigned lsum = 0u;
#pragma unroll
    for (int i = 0; i < 16; ++i) { lc[i] = hist[t * 16 + i]; lsum += lc[i]; }
    s[t] = lsum;
    __syncthreads();
    block_scan256(s);
    unsigned incl = s[t], excl = incl - lsum;
    if (lsum > 0u && excl <= rank_in && rank_in < incl) {
        unsigned r = rank_in - excl;
#pragma unroll
        for (int i = 0; i < 16; ++i) {
            if (r < lc[i]) { shbr[0] = (unsigned)(t * 16 + i); shbr[1] = r; break; }
            r -= lc[i];
        }
    }
    __syncthreads();
    sub = shbr[0];
    rank_out = shbr[1];
    __syncthreads();
}

__global__ void __launch_bounds__(256)
hist12_kernel(const unsigned* __restrict__ keys, Ctrl* __restrict__ c,
              const int* __restrict__ factor_p, int n) {
    __shared__ unsigned s[256];
    __shared__ unsigned shbr[2];
    __shared__ unsigned h[4096];   // 16 KB
    const int t = threadIdx.x;

    unsigned rank; bool use_thr;
    rank_params(c, factor_p[0], n, rank, use_thr);
    unsigned b3, rank1;
    select_byte3(c, rank, s, shbr, b3, rank1);

    for (int i = t; i < 4096; i += 256) h[i] = 0u;
    __syncthreads();

    const int stride = gridDim.x * blockDim.x;
    for (int i = blockIdx.x * blockDim.x + t; i < n; i += stride) {
        unsigned k = keys[i];
        if ((k >> 24) == b3) atomicAdd(&h[(k >> 12) & 0xFFFu], 1u);
    }
    __syncthreads();
    for (int i = t; i < 4096; i += 256)
        if (h[i]) atomicAdd(&c->hist12[i], h[i]);
}

__global__ void __launch_bounds__(256)
reduceF_kernel(const unsigned* __restrict__ keys, const int* __restrict__ label,
               const float* __restrict__ nll, Ctrl* __restrict__ c,
               const int* __restrict__ factor_p, int n, float* __restrict__ out) {
    __shared__ unsigned s[256];
    __shared__ unsigned shbr[2];
    __shared__ double sd[4];
    __shared__ int    si[4];
    const int t = threadIdx.x, lane = t & 63, wid = t >> 6;

    unsigned rank; bool use_thr;
    rank_params(c, factor_p[0], n, rank, use_thr);
    unsigned b3, rank1;
    select_byte3(c, rank, s, shbr, b3, rank1);
    unsigned sub = 0u, rank2 = 0u;
    if (use_thr) select_12(c->hist12, rank1, s, shbr, sub, rank2);
    const unsigned prefix20 = (b3 << 12) | sub;

    double local = 0.0;
    int cntl = 0;
    const int stride = gridDim.x * blockDim.x;
    if (use_thr) {
        // is_pos <=> dkey == 0xFF800000 (-inf encoding; scores finite -> exact)
        for (int i = blockIdx.x * blockDim.x + t; i < n; i += stride) {
            unsigned k = keys[i];
            float nl = nll[i];
            unsigned top20 = k >> 12;
            if (k == 0xFF800000u || top20 < prefix20) { local += (double)nl; cntl++; }
            else if (top20 == prefix20) {
                atomicAdd(&c->bcnt[k & 0xFFFu], 1u);
                atomicAdd(&c->bsum[k & 0xFFFu], nl);
            }
        }
    } else {
        for (int i = blockIdx.x * blockDim.x + t; i < n; i += stride) {
            if (label[i] != -1) { local += (double)nll[i]; cntl++; }
        }
    }
#pragma unroll
    for (int off = 32; off > 0; off >>= 1) {
        local += __shfl_down(local, off);
        cntl  += __shfl_down(cntl, off);
    }
    if (lane == 0) { sd[wid] = local; si[wid] = cntl; }
    __syncthreads();
    __shared__ int s_last;
    if (t == 0) {
        atomicAdd(&c->sum, sd[0] + sd[1] + sd[2] + sd[3]);
        atomicAdd(&c->cnt, (unsigned)(si[0] + si[1] + si[2] + si[3]));
        __threadfence();
        unsigned d = atomicAdd(&c->done, 1u);
        s_last = (d == gridDim.x - 1) ? 1 : 0;
    }
    __syncthreads();
    if (!s_last) return;

    // last block: resolve low 12 bits from buckets, write loss
    __threadfence();
    __shared__ double   fssum;
    __shared__ unsigned fscnt;
    if (t == 0) { fssum = 0.0; fscnt = 0u; }
    __syncthreads();
    if (use_thr) {
        unsigned bstar, dummy;
        select_12(c->bcnt, rank2, s, shbr, bstar, dummy);
        double fsl = 0.0; unsigned fcl = 0u;
        for (int i = t; i < 4096; i += 256)
            if ((unsigned)i <= bstar) { fcl += c->bcnt[i]; fsl += (double)c->bsum[i]; }
#pragma unroll
        for (int off = 32; off > 0; off >>= 1) {
            fsl += __shfl_down(fsl, off);
            fcl += __shfl_down(fcl, off);
        }
        if (lane == 0) { sd[wid] = fsl; si[wid] = (int)fcl; }
        __syncthreads();
        if (t == 0) {
            fssum = sd[0] + sd[1] + sd[2] + sd[3];
            fscnt = (unsigned)(si[0] + si[1] + si[2] + si[3]);
        }
        __syncthreads();
    }
    if (t == 0) {
        double sm = c->sum + fssum;
        unsigned ctn = c->cnt + fscnt;
        double denom = (ctn == 0u) ? 1.0 : (double)ctn;
        out[0] = (float)(sm / denom);
    }
}

extern "C" void kernel_launch(void* const* d_in, const int* in_sizes, int n_in,
                              void* d_out, int out_size, void* d_ws, size_t ws_size,
                              hipStream_t stream) {
    const float* pred = (const float*)d_in[0];
    const int* label  = (const int*)d_in[1];
    const int* factor = (const int*)d_in[2];
    int n = in_sizes[1];
    float* out = (float*)d_out;

    char* ws = (char*)d_ws;
    Ctrl* c  = (Ctrl*)ws;                    // real control state
    Ctrl* cd = (Ctrl*)(ws + 65536);          // dummy (never read)
    unsigned* keys   = (unsigned*)(ws + 131072);
    float*    nll    = (float*)(ws + 131072 + (size_t)n * 4);
    unsigned* keys_d = (unsigned*)(ws + 131072 + (size_t)n * 8);
    float*    nll_d  = (float*)(ws + 131072 + (size_t)n * 12);

    init_kernel<<<64, 256, 0, stream>>>((unsigned*)c, (int)(sizeof(Ctrl) / 4));
    row_kernel<<<2048, 256, 0, stream>>>((const f4*)pred, label, keys, nll, c,
                                         keys_d, nll_d, cd, n);
    hist12_kernel<<<1024, 256, 0, stream>>>(keys, c, factor, n);
    reduceF_kernel<<<1024, 256, 0, stream>>>(keys, label, nll, c, factor, n, out);
}

// Round 12
// 165.472 us; speedup vs baseline: 1.5872x; 1.5872x over previous
//
#include <hip/hip_runtime.h>

// OHEM loss: exact k-th order statistic via 8+12-bit radix select on a
// monotonic key, fused log-softmax NLL, masked mean.  4 dispatches
// (r7-validated skeleton). Row kernel: r7 LDS-staging structure with
//   - XCD-chunked block swizzle (T1): each XCD's blocks read one contiguous
//     region per sweep (DRAM page locality on the cold 256MB stream)
//   - TILE=128 / 128-thread blocks -> 8 independent stage/compute pipelines
//     per CU (was 4) at the same 50% occupancy cap
//   - tree max / 4-chain exp (shorter serial VALU chains)
//   - pred[row][label] via one LDS read (replaces 31 cndmask chain)
// hist12 / reduceF / init are r7-verbatim (validated, off the critical path).

typedef float f4 __attribute__((ext_vector_type(4)));

#define TILE_ROWS   128
#define ROW_F4      9      // 8 data f4 + 1 pad f4 -> conflict-free b128 r/w
#define ROW_THREADS 128
#define ROW_BLOCKS  4096   // multiple of 8 (XCD swizzle) ; 18.4KB LDS -> 8/CU

struct Ctrl {
    unsigned hist8[256];
    unsigned hist12[4096];
    unsigned bcnt[4096];     // low-12 counts within selected 20-bit prefix
    float    bsum[4096];     // nll sums per low-12 bucket
    unsigned pos_num;
    unsigned cnt;
    unsigned done;
    unsigned pad;
    double   sum;
};

__global__ void init_kernel(unsigned* w, int words) {
    for (int i = threadIdx.x + blockIdx.x * blockDim.x; i < words;
         i += blockDim.x * gridDim.x)
        w[i] = 0u;
}

// Wave-aggregated LDS histogram add (top byte has few distinct values).
__device__ inline void wave_hist_add(unsigned* h, unsigned bucket) {
    unsigned long long todo = __ballot(1);
    while (todo) {
        int leader = (int)__builtin_ctzll(todo);
        unsigned b = __shfl(bucket, leader);
        unsigned long long same = __ballot(bucket == b) & todo;
        if ((int)(threadIdx.x & 63) == leader)
            atomicAdd(&h[b], (unsigned)__popcll(same));
        todo &= ~same;
    }
}

__global__ void __launch_bounds__(ROW_THREADS)
row_kernel(const f4* __restrict__ pred4, const int* __restrict__ label,
           unsigned* __restrict__ keys, float* __restrict__ nll,
           Ctrl* __restrict__ c, int n) {
    __shared__ f4 tile[TILE_ROWS * ROW_F4];   // 18.4 KB
    __shared__ unsigned h[256];
    __shared__ int wsum[2];
    const int tid = threadIdx.x;
    h[tid] = 0u; h[tid + 128] = 0u;
    __syncthreads();

    // XCD-chunked swizzle: blocks with bid%8==k (same XCD under round-robin
    // dispatch) get contiguous work -> each XCD reads one contiguous region.
    const unsigned B   = gridDim.x;
    const unsigned swz = (blockIdx.x & 7u) * (B >> 3) + (blockIdx.x >> 3);

    const int tile_stride = B * TILE_ROWS;
    int pos_local = 0;

    for (int tbase = (int)swz * TILE_ROWS; tbase < n; tbase += tile_stride) {
        // stage 128 rows x 128B = 16KB, 8 loads/thread, coalesced 1KB/wave-inst
#pragma unroll
        for (int k = 0; k < 8; ++k) {
            int idx = (k << 7) + tid;                 // 0..1023
            f4 v = pred4[(size_t)tbase * 8 + idx];
            tile[(idx >> 3) * ROW_F4 + (idx & 7)] = v;
        }
        __syncthreads();

        int row = tbase + tid;
        float r[32];
#pragma unroll
        for (int j = 0; j < 8; ++j) {
            f4 v = tile[tid * ROW_F4 + j];
            r[4 * j + 0] = v.x; r[4 * j + 1] = v.y;
            r[4 * j + 2] = v.z; r[4 * j + 3] = v.w;
        }
        // tree max over cols 1..31 (4 parallel chains)
        float m0 = r[1], m1 = r[2], m2 = r[3], m3 = r[4];
#pragma unroll
        for (int j = 5; j <= 28; j += 4) {
            m0 = fmaxf(m0, r[j]);   m1 = fmaxf(m1, r[j+1]);
            m2 = fmaxf(m2, r[j+2]); m3 = fmaxf(m3, r[j+3]);
        }
        m0 = fmaxf(m0, r[29]); m1 = fmaxf(m1, r[30]); m2 = fmaxf(m2, r[31]);
        float m_nb  = fmaxf(fmaxf(m0, m1), fmaxf(m2, m3));
        float m_all = fmaxf(m_nb, r[0]);

        float s0 = 0.f, s1 = 0.f, s2 = 0.f, s3 = 0.f;
#pragma unroll
        for (int j = 0; j < 32; j += 4) {
            s0 += __expf(r[j]   - m_all);  s1 += __expf(r[j+1] - m_all);
            s2 += __expf(r[j+2] - m_all);  s3 += __expf(r[j+3] - m_all);
        }
        float ssum = (s0 + s1) + (s2 + s3);

        int lab = label[row];
        int sl = lab; sl = sl < 0 ? 0 : sl; sl = sl > 31 ? 31 : sl;
        // one LDS read replaces the 31-step cndmask select chain
        float xl = ((const float*)tile)[tid * (ROW_F4 * 4) + sl];

        nll[row] = (m_all + __logf(ssum)) - xl;

        bool is_pos = (lab != 0);
        pos_local += is_pos ? 1 : 0;

        float ns = is_pos ? -__builtin_inff() : m_nb;
        unsigned u    = __float_as_uint(ns);
        unsigned ukey = (u & 0x80000000u) ? ~u : (u | 0x80000000u);
        unsigned dkey = ~ukey;               // ascending dkey = descending float
        keys[row] = dkey;
        wave_hist_add(h, dkey >> 24);

        __syncthreads();   // protect tile before next stage
    }

#pragma unroll
    for (int off = 32; off > 0; off >>= 1)
        pos_local += __shfl_down(pos_local, off);
    if ((tid & 63) == 0) wsum[tid >> 6] = pos_local;
    __syncthreads();
    if (tid == 0)
        atomicAdd(&c->pos_num, (unsigned)(wsum[0] + wsum[1]));
    if (h[tid])       atomicAdd(&c->hist8[tid],       h[tid]);
    if (h[tid + 128]) atomicAdd(&c->hist8[tid + 128], h[tid + 128]);
}

// 256-wide inclusive scan of s[] in LDS (blockDim.x == 256).
__device__ inline void block_scan256(unsigned* s) {
    const int t = threadIdx.x;
#pragma unroll
    for (int off = 1; off < 256; off <<= 1) {
        unsigned v = (t >= off) ? s[t - off] : 0u;
        __syncthreads();
        s[t] += v;
        __syncthreads();
    }
}

__device__ inline void rank_params(const Ctrl* c, int factor, int n,
                                   unsigned& rank, bool& use_thr) {
    long long pos     = (long long)c->pos_num;
    long long neg_sum = pos * (long long)factor;
    long long num_neg = (long long)n - pos;
    long long idx     = neg_sum - 1;
    if (idx < 0) idx = 0;
    if (idx > (long long)n - 1) idx = (long long)n - 1;
    rank    = (unsigned)idx;
    use_thr = (num_neg > neg_sum);
}

__device__ inline void select_byte3(const Ctrl* c, unsigned rank, unsigned* s,
                                    unsigned* shbr, unsigned& b3, unsigned& rank1) {
    const int t = threadIdx.x;
    unsigned cnt8 = c->hist8[t];
    s[t] = cnt8;
    __syncthreads();
    block_scan256(s);
    unsigned incl = s[t], excl = incl - cnt8;
    if (cnt8 > 0u && excl <= rank && rank < incl) {
        shbr[0] = (unsigned)t;
        shbr[1] = rank - excl;
    }
    __syncthreads();
    b3 = shbr[0];
    rank1 = shbr[1];
    __syncthreads();
}

__device__ inline void select_12(const unsigned* hist, unsigned rank_in,
                                 unsigned* s, unsigned* shbr,
                                 unsigned& sub, unsigned& rank_out) {
    const int t = threadIdx.x;
    unsigned lc[16]; unsigned lsum = 0u;
#pragma unroll
    for (int i = 0; i < 16; ++i) { lc[i] = hist[t * 16 + i]; lsum += lc[i]; }
    s[t] = lsum;
    __syncthreads();
    block_scan256(s);
    unsigned incl = s[t], excl = incl - lsum;
    if (lsum > 0u && excl <= rank_in && rank_in < incl) {
        unsigned r = rank_in - excl;
#pragma unroll
        for (int i = 0; i < 16; ++i) {
            if (r < lc[i]) { shbr[0] = (unsigned)(t * 16 + i); shbr[1] = r; break; }
            r -= lc[i];
        }
    }
    __syncthreads();
    sub = shbr[0];
    rank_out = shbr[1];
    __syncthreads();
}

__global__ void __launch_bounds__(256)
hist12_kernel(const unsigned* __restrict__ keys, Ctrl* __restrict__ c,
              const int* __restrict__ factor_p, int n) {
    __shared__ unsigned s[256];
    __shared__ unsigned shbr[2];
    __shared__ unsigned h[4096];   // 16 KB
    const int t = threadIdx.x;

    unsigned rank; bool use_thr;
    rank_params(c, factor_p[0], n, rank, use_thr);
    unsigned b3, rank1;
    select_byte3(c, rank, s, shbr, b3, rank1);

    for (int i = t; i < 4096; i += 256) h[i] = 0u;
    __syncthreads();

    const int stride = gridDim.x * blockDim.x;
    for (int i = blockIdx.x * blockDim.x + t; i < n; i += stride) {
        unsigned k = keys[i];
        if ((k >> 24) == b3) atomicAdd(&h[(k >> 12) & 0xFFFu], 1u);
    }
    __syncthreads();
    for (int i = t; i < 4096; i += 256)
        if (h[i]) atomicAdd(&c->hist12[i], h[i]);
}

__global__ void __launch_bounds__(256)
reduceF_kernel(const unsigned* __restrict__ keys, const int* __restrict__ label,
               const float* __restrict__ nll, Ctrl* __restrict__ c,
               const int* __restrict__ factor_p, int n, float* __restrict__ out) {
    __shared__ unsigned s[256];
    __shared__ unsigned shbr[2];
    __shared__ double sd[4];
    __shared__ int    si[4];
    const int t = threadIdx.x, lane = t & 63, wid = t >> 6;

    unsigned rank; bool use_thr;
    rank_params(c, factor_p[0], n, rank, use_thr);
    unsigned b3, rank1;
    select_byte3(c, rank, s, shbr, b3, rank1);
    unsigned sub = 0u, rank2 = 0u;
    if (use_thr) select_12(c->hist12, rank1, s, shbr, sub, rank2);
    const unsigned prefix20 = (b3 << 12) | sub;

    double local = 0.0;
    int cntl = 0;
    const int stride = gridDim.x * blockDim.x;
    if (use_thr) {
        // is_pos <=> dkey == 0xFF800000 (-inf encoding; scores finite -> exact)
        for (int i = blockIdx.x * blockDim.x + t; i < n; i += stride) {
            unsigned k = keys[i];
            float nl = nll[i];
            unsigned top20 = k >> 12;
            if (k == 0xFF800000u || top20 < prefix20) { local += (double)nl; cntl++; }
            else if (top20 == prefix20) {
                atomicAdd(&c->bcnt[k & 0xFFFu], 1u);
                atomicAdd(&c->bsum[k & 0xFFFu], nl);
            }
        }
    } else {
        for (int i = blockIdx.x * blockDim.x + t; i < n; i += stride) {
            if (label[i] != -1) { local += (double)nll[i]; cntl++; }
        }
    }
#pragma unroll
    for (int off = 32; off > 0; off >>= 1) {
        local += __shfl_down(local, off);
        cntl  += __shfl_down(cntl, off);
    }
    if (lane == 0) { sd[wid] = local; si[wid] = cntl; }
    __syncthreads();
    __shared__ int s_last;
    if (t == 0) {
        atomicAdd(&c->sum, sd[0] + sd[1] + sd[2] + sd[3]);
        atomicAdd(&c->cnt, (unsigned)(si[0] + si[1] + si[2] + si[3]));
        __threadfence();
        unsigned d = atomicAdd(&c->done, 1u);
        s_last = (d == gridDim.x - 1) ? 1 : 0;
    }
    __syncthreads();
    if (!s_last) return;

    // last block: resolve low 12 bits from buckets, write loss
    __threadfence();
    __shared__ double   fssum;
    __shared__ unsigned fscnt;
    if (t == 0) { fssum = 0.0; fscnt = 0u; }
    __syncthreads();
    if (use_thr) {
        unsigned bstar, dummy;
        select_12(c->bcnt, rank2, s, shbr, bstar, dummy);
        double fsl = 0.0; unsigned fcl = 0u;
        for (int i = t; i < 4096; i += 256)
            if ((unsigned)i <= bstar) { fcl += c->bcnt[i]; fsl += (double)c->bsum[i]; }
#pragma unroll
        for (int off = 32; off > 0; off >>= 1) {
            fsl += __shfl_down(fsl, off);
            fcl += __shfl_down(fcl, off);
        }
        if (lane == 0) { sd[wid] = fsl; si[wid] = (int)fcl; }
        __syncthreads();
        if (t == 0) {
            fssum = sd[0] + sd[1] + sd[2] + sd[3];
            fscnt = (unsigned)(si[0] + si[1] + si[2] + si[3]);
        }
        __syncthreads();
    }
    if (t == 0) {
        double sm = c->sum + fssum;
        unsigned ctn = c->cnt + fscnt;
        double denom = (ctn == 0u) ? 1.0 : (double)ctn;
        out[0] = (float)(sm / denom);
    }
}

extern "C" void kernel_launch(void* const* d_in, const int* in_sizes, int n_in,
                              void* d_out, int out_size, void* d_ws, size_t ws_size,
                              hipStream_t stream) {
    const float* pred = (const float*)d_in[0];
    const int* label  = (const int*)d_in[1];
    const int* factor = (const int*)d_in[2];
    int n = in_sizes[1];
    float* out = (float*)d_out;

    char* ws = (char*)d_ws;
    Ctrl* c = (Ctrl*)ws;
    unsigned* keys = (unsigned*)(ws + 65536);
    float* nll = (float*)(ws + 65536 + (size_t)n * 4);

    init_kernel<<<64, 256, 0, stream>>>((unsigned*)c, (int)(sizeof(Ctrl) / 4));
    row_kernel<<<ROW_BLOCKS, ROW_THREADS, 0, stream>>>((const f4*)pred, label,
                                                       keys, nll, c, n);
    hist12_kernel<<<1024, 256, 0, stream>>>(keys, c, factor, n);
    reduceF_kernel<<<1024, 256, 0, stream>>>(keys, label, nll, c, factor, n, out);
}